// Round 10
// baseline (353.046 us; speedup 1.0000x reference)
//
#include <hip/hip_runtime.h>
#include <math.h>
#include <stdint.h>

#define T_TOK 8192
#define NEXP  256
#define HD    7168
#define PLANE ((size_t)T_TOK * NEXP)
#define SCALE 4096.0f
#define INV_S2 (1.0f / 16777216.0f)   // 2^-24
#define BM 64
#define BK 32                          // fp32 K-columns per step
#define NSTEP_TOT (HD / BK)            // 224
#define IMG_STEP_H 16384               // halfs per K-step image (32 KB)

typedef _Float16 h8  __attribute__((ext_vector_type(8)));
typedef float f32x16 __attribute__((ext_vector_type(16)));

// ---- W -> f16 hi/lo image, [t][ks(2)][pl(2)][col(256)][kg(2)] in 8-half chunks ----
__global__ __launch_bounds__(256) void wconv(const float* __restrict__ W,
                                             _Float16* __restrict__ img) {
  const int cc  = blockIdx.x * 256 + threadIdx.x;
  const int t   = cc >> 11;
  const int c   = cc & 2047;
  const int ks  = c >> 10;
  const int pl  = (c >> 9) & 1;
  const int col = (c >> 1) & 255;
  const int kg  = c & 1;
  const int k   = t * BK + ks * 16 + kg * 8;

  const float* src = W + (size_t)col * HD + k;
  const float4 v0 = *(const float4*)src;
  const float4 v1 = *(const float4*)(src + 4);
  const float xs[8] = {v0.x, v0.y, v0.z, v0.w, v1.x, v1.y, v1.z, v1.w};
  h8 out;
#pragma unroll
  for (int j = 0; j < 8; ++j) {
    const float v = xs[j] * SCALE;
    const _Float16 hh = (_Float16)v;
    out[j] = pl ? (_Float16)(v - (float)hh) : hh;
  }
  *(h8*)(img + (size_t)cc * 8) = out;
}

// ---- Router GEMM (template ablation): V0=full V1=A-path-only V2=B-path-only V3=MFMA-only ----
template <int V>
__global__ __launch_bounds__(256) void router_gemm_t(
    const float* __restrict__ X, const _Float16* __restrict__ img,
    float* __restrict__ partial, int S, float opq) {
  constexpr bool HAS_A = (V == 0 || V == 1);   // A staging via LDS + barrier + cvt
  constexpr bool HAS_B = (V == 0 || V == 2);   // B loads from L2 image

  __shared__ _Float16 As[2][2][BM][BK];        // 16 KB (elided by compiler when !HAS_A)

  const int tid = threadIdx.x;
  const int id  = blockIdx.x;
  const int sb  = id % S;
  const int mb  = id / S;

  const int row0  = mb * BM;
  const int nstep = (HD / S) / BK;
  const int tbase = sb * nstep;

  const int lane = tid & 63, wv = tid >> 6;
  const int r31 = lane & 31, kg = lane >> 5;

  const int sm = tid >> 2;
  const int sk = tid & 3;
  const int spA = sk ^ ((sm >> 1) & 3);

  const float* Ap = X + (size_t)(row0 + sm) * HD + tbase * BK + sk * 8;
  const _Float16* imgBase = img + (size_t)tbase * IMG_STEP_H;
  const int colb = wv * 64 + r31;

  h8 splat;   // runtime-opaque: prevents constant folding / DCE of the MFMA chain
#pragma unroll
  for (int j = 0; j < 8; ++j) splat[j] = (_Float16)opq;

  f32x16 acc[2][2];
#pragma unroll
  for (int i = 0; i < 2; ++i)
#pragma unroll
    for (int j = 0; j < 2; ++j) acc[i][j] = (f32x16)(0.f);

#define CVT_WRITE_A(b, va, vb)                                                 \
  {                                                                            \
    const float xs[8] = {va.x, va.y, va.z, va.w, vb.x, vb.y, vb.z, vb.w};      \
    h8 hv, lv_;                                                                \
    _Pragma("unroll")                                                          \
    for (int j = 0; j < 8; ++j) {                                              \
      const float v = xs[j] * SCALE;                                           \
      const _Float16 hh = (_Float16)v;                                         \
      hv[j] = hh; lv_[j] = (_Float16)(v - (float)hh);                          \
    }                                                                          \
    *(h8*)&As[b][0][sm][spA * 8] = hv;                                         \
    *(h8*)&As[b][1][sm][spA * 8] = lv_;                                        \
  }

  if constexpr (HAS_A) {
    const float4 a0 = *(const float4*)(Ap);
    const float4 a1 = *(const float4*)(Ap + 4);
    CVT_WRITE_A(0, a0, a1);
  }

  for (int t = 0; t < nstep; ++t) {
    const int cur = t & 1;
    const bool more = (t + 1 < nstep);
    if constexpr (HAS_A) __syncthreads();

    h8 b[2][2][2];                           // [ks][pl][ni]
    if constexpr (HAS_B) {
      const _Float16* bp = imgBase + (size_t)t * IMG_STEP_H;
#pragma unroll
      for (int ks = 0; ks < 2; ++ks)
#pragma unroll
        for (int pl = 0; pl < 2; ++pl)
#pragma unroll
          for (int ni = 0; ni < 2; ++ni)
            b[ks][pl][ni] = *(const h8*)(bp + ((size_t)((ks * 2 + pl) * 256 + colb + ni * 32) * 16) + kg * 8);
    } else {
#pragma unroll
      for (int ks = 0; ks < 2; ++ks)
#pragma unroll
        for (int pl = 0; pl < 2; ++pl)
#pragma unroll
          for (int ni = 0; ni < 2; ++ni) b[ks][pl][ni] = splat;
    }

    float4 a0, a1;
    if constexpr (HAS_A) {
      if (more) {
        const float* ap = Ap + (size_t)(t + 1) * BK;
        a0 = *(const float4*)(ap);
        a1 = *(const float4*)(ap + 4);
      }
    }

    h8 aH[2][2], aL[2][2];                   // [ks][mi]
    if constexpr (HAS_A) {
#pragma unroll
      for (int ks = 0; ks < 2; ++ks)
#pragma unroll
        for (int mi = 0; mi < 2; ++mi) {
          const int row = mi * 32 + r31;
          const int sp  = (ks * 2 + kg) ^ ((row >> 1) & 3);
          aH[ks][mi] = *(const h8*)&As[cur][0][row][sp * 8];
          aL[ks][mi] = *(const h8*)&As[cur][1][row][sp * 8];
        }
    } else {
#pragma unroll
      for (int ks = 0; ks < 2; ++ks)
#pragma unroll
        for (int mi = 0; mi < 2; ++mi) { aH[ks][mi] = splat; aL[ks][mi] = splat; }
    }

#pragma unroll
    for (int ks = 0; ks < 2; ++ks) {
#pragma unroll
      for (int mi = 0; mi < 2; ++mi)
#pragma unroll
        for (int ni = 0; ni < 2; ++ni)
          acc[mi][ni] = __builtin_amdgcn_mfma_f32_32x32x16_f16(aH[ks][mi], b[ks][0][ni], acc[mi][ni], 0, 0, 0);
#pragma unroll
      for (int mi = 0; mi < 2; ++mi)
#pragma unroll
        for (int ni = 0; ni < 2; ++ni)
          acc[mi][ni] = __builtin_amdgcn_mfma_f32_32x32x16_f16(aL[ks][mi], b[ks][0][ni], acc[mi][ni], 0, 0, 0);
#pragma unroll
      for (int mi = 0; mi < 2; ++mi)
#pragma unroll
        for (int ni = 0; ni < 2; ++ni)
          acc[mi][ni] = __builtin_amdgcn_mfma_f32_32x32x16_f16(aH[ks][mi], b[ks][1][ni], acc[mi][ni], 0, 0, 0);
    }

    if constexpr (HAS_A) {
      if (more) CVT_WRITE_A(cur ^ 1, a0, a1);
    }
  }

  // Epilogue (keeps acc live in all variants)
  float* base = partial + (size_t)sb * PLANE;
#pragma unroll
  for (int mi = 0; mi < 2; ++mi)
#pragma unroll
    for (int ni = 0; ni < 2; ++ni) {
      const int col = wv * 64 + ni * 32 + r31;
#pragma unroll
      for (int reg = 0; reg < 16; ++reg) {
        const int rr  = (reg & 3) + 8 * (reg >> 2) + 4 * kg;
        const int row = row0 + mi * 32 + rr;
        base[(size_t)row * NEXP + col] = acc[mi][ni][reg];
      }
    }
}

// ---------------- Gating: one wave per token; sums S partial planes ----------------
__global__ __launch_bounds__(256) void gate_kernel(const float* __restrict__ logits,
                                                   const float* __restrict__ bias,
                                                   float* __restrict__ out_w,
                                                   float* __restrict__ out_e, int S) {
    const int wave = threadIdx.x >> 6;
    const int lane = threadIdx.x & 63;
    const int t = blockIdx.x * 4 + wave;
    if (t >= T_TOK) return;

    float l4[4] = {0.f, 0.f, 0.f, 0.f};
    for (int s = 0; s < S; ++s) {  // fixed order -> deterministic
        const float4 v = *(const float4*)(&logits[(size_t)s * PLANE + (size_t)t * NEXP + lane * 4]);
        l4[0] += v.x; l4[1] += v.y; l4[2] += v.z; l4[3] += v.w;
    }
    const float4 bv = *(const float4*)(&bias[lane * 4]);

    float s4[4], c[4];
#pragma unroll
    for (int j = 0; j < 4; ++j) s4[j] = 1.f / (1.f + expf(-l4[j] * INV_S2));
    c[0] = s4[0] + bv.x;
    c[1] = s4[1] + bv.y;
    c[2] = s4[2] + bv.z;
    c[3] = s4[3] + bv.w;

    float a = fmaxf(c[0], c[1]), b = fminf(c[0], c[1]);
    float d = fmaxf(c[2], c[3]), e = fminf(c[2], c[3]);
    float m1 = fmaxf(a, d);
    float m2 = fmaxf(fminf(a, d), fmaxf(b, e));
#pragma unroll
    for (int off = 1; off < 8; off <<= 1) {
        const float o1 = __shfl_xor(m1, off);
        const float o2 = __shfl_xor(m2, off);
        const float n1 = fmaxf(m1, o1);
        const float n2 = fmaxf(fminf(m1, o1), fmaxf(m2, o2));
        m1 = n1; m2 = n2;
    }
    const float gs = m1 + m2;
    const int   g  = lane >> 3;

    int rank = 0;
#pragma unroll
    for (int gg = 0; gg < 8; ++gg) {
        const float og = __shfl(gs, gg * 8);
        rank += (og > gs) || (og == gs && gg < g);
    }
    const bool gsel = rank < 4;

    float v[4];
#pragma unroll
    for (int j = 0; j < 4; ++j) v[j] = gsel ? c[j] : 0.0f;

    float selw = 0.f;
    int   seli = 0;
    float wsum = 0.f;

#pragma unroll
    for (int k = 0; k < 8; ++k) {
        float bvv = v[0]; int bi = lane * 4; float br = s4[0];
#pragma unroll
        for (int j = 1; j < 4; ++j) {
            if (v[j] > bvv) { bvv = v[j]; bi = lane * 4 + j; br = s4[j]; }
        }
#pragma unroll
        for (int off = 32; off > 0; off >>= 1) {
            const float ov = __shfl_xor(bvv, off);
            const int   oi = __shfl_xor(bi, off);
            const float orr = __shfl_xor(br, off);
            if (ov > bvv || (ov == bvv && oi < bi)) { bvv = ov; bi = oi; br = orr; }
        }
        if (lane == k) { selw = br; seli = bi; }
        wsum += br;
        const int rem = bi - lane * 4;
#pragma unroll
        for (int j = 0; j < 4; ++j)
            if (rem == j) v[j] = -INFINITY;
    }

    if (lane < 8) {
        const float w = selw / (wsum + 1e-20f) * 2.5f;
        out_w[(size_t)t * 8 + lane] = w;
        out_e[(size_t)t * 8 + lane] = (float)seli;
    }
}

extern "C" void kernel_launch(void* const* d_in, const int* in_sizes, int n_in,
                              void* d_out, int out_size, void* d_ws, size_t ws_size,
                              hipStream_t stream) {
    const float* X    = (const float*)d_in[0];
    const float* W    = (const float*)d_in[1];
    const float* bias = (const float*)d_in[2];
    float* out = (float*)d_out;

    _Float16* img = (_Float16*)d_ws;
    const size_t woff = (size_t)NSTEP_TOT * IMG_STEP_H * sizeof(_Float16);   // 7,340,032 B
    float* partial = (float*)((char*)d_ws + woff);

    int S = 1;
    if (ws_size >= woff + 8 * PLANE * sizeof(float)) S = 8;
    else if (ws_size >= woff + 4 * PLANE * sizeof(float)) S = 4;
    else if (ws_size >= woff + 2 * PLANE * sizeof(float)) S = 2;

    wconv<<<dim3(NSTEP_TOT * 2048 / 256), 256, 0, stream>>>(W, img);
    router_gemm_t<0><<<dim3((T_TOK / BM) * S), 256, 0, stream>>>(X, img, partial, S, 1.0f);
    gate_kernel<<<dim3(T_TOK / 4), 256, 0, stream>>>(partial, bias, out, out + (size_t)T_TOK * 8, S);

    // ---- diagnostic ablations (outputs discarded; results never read by gate) ----
    const size_t dummy_off = woff + (size_t)8 * PLANE * sizeof(float);
    if (ws_size >= dummy_off + (size_t)8 * PLANE * sizeof(float)) {
      float* dummy = (float*)((char*)d_ws + dummy_off);
      router_gemm_t<1><<<dim3((T_TOK / BM) * S), 256, 0, stream>>>(X, img, dummy, S, 1.0f);  // A-path only
      router_gemm_t<2><<<dim3((T_TOK / BM) * S), 256, 0, stream>>>(X, img, dummy, S, 1.0f);  // B-path only
      router_gemm_t<3><<<dim3((T_TOK / BM) * S), 256, 0, stream>>>(X, img, dummy, S, 1.0f);  // MFMA only
    }
}

// Round 11
// 135.240 us; speedup vs baseline: 2.6105x; 2.6105x over previous
//
#include <hip/hip_runtime.h>
#include <math.h>
#include <stdint.h>

#define T_TOK 8192
#define NEXP  256
#define HD    7168
#define PLANE ((size_t)T_TOK * NEXP)
#define SCALE 4096.0f
#define INV_S2 (1.0f / 16777216.0f)   // 2^-24
#define BM 256
#define BK 32                          // fp32 K-columns per step
#define NSTEP_TOT (HD / BK)            // 224
#define BIMG_STEP 32768                // bytes per K-step: 2 planes * 256 rows * 4 slots * 16B

typedef _Float16 h8  __attribute__((ext_vector_type(8)));
typedef float f32x16 __attribute__((ext_vector_type(16)));
typedef __attribute__((address_space(3))) uint8_t       lds_t;
typedef __attribute__((address_space(1))) const uint8_t gbl_t;

// ---- W -> pre-swizzled f16 hi/lo LDS image [t][hl][row(256)][slot(4)] (16B chunks) ----
// content of chunk (hl,row,sp): plane hl of W[row][t*32 + (sp ^ ((row>>1)&3))*8 .. +7] * SCALE
__global__ __launch_bounds__(256) void wconv(const float* __restrict__ W,
                                             _Float16* __restrict__ img) {
  const int cc  = blockIdx.x * 256 + threadIdx.x;
  const int t   = cc >> 11;
  const int c   = cc & 2047;
  const int hl  = c >> 10;
  const int rem = c & 1023;
  const int row = rem >> 2;
  const int sp  = rem & 3;
  const int sl  = sp ^ ((row >> 1) & 3);
  const int k   = t * BK + sl * 8;

  const float* src = W + (size_t)row * HD + k;
  const float4 v0 = *(const float4*)src;
  const float4 v1 = *(const float4*)(src + 4);
  const float xs[8] = {v0.x, v0.y, v0.z, v0.w, v1.x, v1.y, v1.z, v1.w};
  h8 out;
#pragma unroll
  for (int j = 0; j < 8; ++j) {
    const float v = xs[j] * SCALE;
    const _Float16 hh = (_Float16)v;
    out[j] = hl ? (_Float16)(v - (float)hh) : hh;
  }
  *(h8*)(img + (size_t)cc * 8) = out;
}

// ---- Router GEMM: 256x256 tile, 8 waves (2Mx4N, 128x64 each), 4-phase m201-style schedule ----
__global__ __launch_bounds__(512, 2) void router_gemm(
    const float* __restrict__ X, const _Float16* __restrict__ img,
    float* __restrict__ partial, int S) {
  __shared__ __align__(1024) _Float16 As[2][2][BM][BK];    // 64 KB
  __shared__ __align__(1024) _Float16 Bs[2][2][NEXP][BK];  // 64 KB

  const int tid = threadIdx.x;
  const int id  = blockIdx.x;
  const int sb  = id % S;        // S=8: one K-slice per XCD -> 0.9 MB img slice L2-hot
  const int mb  = id / S;

  const int row0  = mb * BM;
  const int nstep = (HD / S) / BK;
  const int tbase = sb * nstep;

  const int lane = tid & 63, wv = tid >> 6;
  const int wm = wv >> 2, wn = wv & 3;        // wave tile 128(M) x 64(N)
  const int r31 = lane & 31, kg = lane >> 5;

  const int sm = tid >> 1;                    // A staging row 0..255
  const int sk = tid & 1;                     // 16-float half-row

  const float* Ap = X + (size_t)(row0 + sm) * HD + tbase * BK + sk * 16;
  const uint8_t* imgB = (const uint8_t*)img + (size_t)tbase * BIMG_STEP + tid * 16;

  f32x16 acc[4][2];
#pragma unroll
  for (int i = 0; i < 4; ++i)
#pragma unroll
    for (int j = 0; j < 2; ++j) acc[i][j] = (f32x16)(0.f);

#define LOAD_A(t)                                                              \
  {                                                                            \
    const float* ap = Ap + (size_t)(t) * BK;                                   \
    a0 = *(const float4*)(ap);                                                 \
    a1 = *(const float4*)(ap + 4);                                             \
    a2 = *(const float4*)(ap + 8);                                             \
    a3 = *(const float4*)(ap + 12);                                            \
  }

#define STAGE_B2(t, b, i0)                                                     \
  {                                                                            \
    const uint8_t* g = imgB + (size_t)(t) * BIMG_STEP;                         \
    uint8_t* l = (uint8_t*)&Bs[b][0][0][0] + tid * 16;                         \
    __builtin_amdgcn_global_load_lds((gbl_t*)(uintptr_t)(g + (i0) * 8192),     \
                                     (lds_t*)(uintptr_t)(l + (i0) * 8192), 16, 0, 0); \
    __builtin_amdgcn_global_load_lds((gbl_t*)(uintptr_t)(g + ((i0) + 1) * 8192), \
                                     (lds_t*)(uintptr_t)(l + ((i0) + 1) * 8192), 16, 0, 0); \
  }

#define CVT_WRITE_A(b)                                                         \
  {                                                                            \
    const float xs[16] = {a0.x, a0.y, a0.z, a0.w, a1.x, a1.y, a1.z, a1.w,      \
                          a2.x, a2.y, a2.z, a2.w, a3.x, a3.y, a3.z, a3.w};     \
    h8 hv0, hv1, lv0, lv1;                                                     \
    _Pragma("unroll")                                                          \
    for (int j = 0; j < 8; ++j) {                                              \
      const float v = xs[j] * SCALE;                                           \
      const _Float16 hh = (_Float16)v;                                         \
      hv0[j] = hh; lv0[j] = (_Float16)(v - (float)hh);                         \
    }                                                                          \
    _Pragma("unroll")                                                          \
    for (int j = 0; j < 8; ++j) {                                              \
      const float v = xs[8 + j] * SCALE;                                       \
      const _Float16 hh = (_Float16)v;                                         \
      hv1[j] = hh; lv1[j] = (_Float16)(v - (float)hh);                         \
    }                                                                          \
    const int s0 = (sk * 2) ^ ((sm >> 1) & 3);                                 \
    const int s1 = (sk * 2 + 1) ^ ((sm >> 1) & 3);                             \
    *(h8*)&As[b][0][sm][s0 * 8] = hv0;                                         \
    *(h8*)&As[b][0][sm][s1 * 8] = hv1;                                         \
    *(h8*)&As[b][1][sm][s0 * 8] = lv0;                                         \
    *(h8*)&As[b][1][sm][s1 * 8] = lv1;                                         \
  }

#define READ_B(ks, dst)                                                        \
  _Pragma("unroll")                                                            \
  for (int ni = 0; ni < 2; ++ni)                                               \
    _Pragma("unroll")                                                          \
    for (int pl = 0; pl < 2; ++pl) {                                           \
      const int col = wn * 64 + ni * 32 + r31;                                 \
      const int sp  = ((ks) * 2 + kg) ^ ((col >> 1) & 3);                      \
      dst[ni][pl] = *(const h8*)&Bs[cur][pl][col][sp * 8];                     \
    }

#define READ_A(ks, mbase, dst)                                                 \
  _Pragma("unroll")                                                            \
  for (int mi = 0; mi < 2; ++mi)                                               \
    _Pragma("unroll")                                                          \
    for (int pl = 0; pl < 2; ++pl) {                                           \
      const int row = wm * 128 + ((mbase) + mi) * 32 + r31;                    \
      const int sp  = ((ks) * 2 + kg) ^ ((row >> 1) & 3);                      \
      dst[mi][pl] = *(const h8*)&As[cur][pl][row][sp * 8];                     \
    }

#define MFMA12(aF, bF, mbase)                                                  \
  __builtin_amdgcn_s_setprio(1);                                               \
  _Pragma("unroll")                                                            \
  for (int mi = 0; mi < 2; ++mi)                                               \
    _Pragma("unroll")                                                          \
    for (int ni = 0; ni < 2; ++ni)                                             \
      acc[(mbase) + mi][ni] = __builtin_amdgcn_mfma_f32_32x32x16_f16(          \
          aF[mi][0], bF[ni][0], acc[(mbase) + mi][ni], 0, 0, 0);               \
  _Pragma("unroll")                                                            \
  for (int mi = 0; mi < 2; ++mi)                                               \
    _Pragma("unroll")                                                          \
    for (int ni = 0; ni < 2; ++ni)                                             \
      acc[(mbase) + mi][ni] = __builtin_amdgcn_mfma_f32_32x32x16_f16(          \
          aF[mi][1], bF[ni][0], acc[(mbase) + mi][ni], 0, 0, 0);               \
  _Pragma("unroll")                                                            \
  for (int mi = 0; mi < 2; ++mi)                                               \
    _Pragma("unroll")                                                          \
    for (int ni = 0; ni < 2; ++ni)                                             \
      acc[(mbase) + mi][ni] = __builtin_amdgcn_mfma_f32_32x32x16_f16(          \
          aF[mi][0], bF[ni][1], acc[(mbase) + mi][ni], 0, 0, 0);               \
  __builtin_amdgcn_s_setprio(0);

#define FENCE asm volatile("" ::: "memory");
#define BAR   __builtin_amdgcn_s_barrier();
#define WAITL0 asm volatile("s_waitcnt lgkmcnt(0)" ::: "memory"); __builtin_amdgcn_sched_barrier(0);

  // ---- prologue: fully stage step 0 into buf 0 ----
  {
    float4 a0, a1, a2, a3;
    LOAD_A(0);
    STAGE_B2(0, 0, 0);
    STAGE_B2(0, 0, 2);
    asm volatile("s_waitcnt vmcnt(4)" ::: "memory");   // A regs ready
    CVT_WRITE_A(0);
    asm volatile("s_waitcnt vmcnt(0) lgkmcnt(0)" ::: "memory");
    BAR;
  }

  for (int t = 0; t < nstep; ++t) {
    const int cur = t & 1;
    const int nxt = cur ^ 1;
    const bool more = (t + 1 < nstep);

    h8 b0[2][2], b1[2][2], aA[2][2], aB[2][2];
    float4 a0, a1, a2, a3;

    // ---- P0: reads(B ks0 + A ks0 mi01) | issue A-loads(t+1) ----
    READ_B(0, b0);
    READ_A(0, 0, aA);
    if (more) LOAD_A(t + 1);
    FENCE; BAR; WAITL0;
    MFMA12(aA, b0, 0);
    FENCE; BAR;

    // ---- P1: reads(A ks0 mi23) | issue B-lds half 1 ----
    READ_A(0, 2, aB);
    if (more) STAGE_B2(t + 1, nxt, 0);
    FENCE; BAR; WAITL0;
    MFMA12(aB, b0, 2);
    FENCE; BAR;

    // ---- P2: reads(B ks1 + A ks1 mi01) | issue B-lds half 2 ----
    READ_B(1, b1);
    READ_A(1, 0, aA);
    if (more) STAGE_B2(t + 1, nxt, 2);
    FENCE; BAR; WAITL0;
    MFMA12(aA, b1, 0);
    FENCE; BAR;

    // ---- P3: reads(A ks1 mi23) | cvt+write A(t+1) behind vmcnt(4) ----
    READ_A(1, 2, aB);
    if (more) {
      asm volatile("s_waitcnt vmcnt(4)" ::: "memory");  // A regs done; 4 B-lds still in flight
      __builtin_amdgcn_sched_barrier(0);
      CVT_WRITE_A(nxt);
    }
    asm volatile("s_waitcnt lgkmcnt(0)" ::: "memory");  // my reads + my A-writes retired
    __builtin_amdgcn_sched_barrier(0);
    BAR;                                                // all waves' A-writes published
    MFMA12(aB, b1, 2);
    if (more) asm volatile("s_waitcnt vmcnt(0)" ::: "memory");  // B-DMA (issued 2 phases ago) landed
    FENCE; BAR;                                         // Bs[nxt]/As[nxt] ready for t+1
  }

  // Epilogue. 32x32 C/D: col = lane&31, row = (reg&3) + 8*(reg>>2) + 4*(lane>>5)
  float* base = partial + (size_t)sb * PLANE;
#pragma unroll
  for (int mi = 0; mi < 4; ++mi)
#pragma unroll
    for (int ni = 0; ni < 2; ++ni) {
      const int col = wn * 64 + ni * 32 + r31;
#pragma unroll
      for (int reg = 0; reg < 16; ++reg) {
        const int rr  = (reg & 3) + 8 * (reg >> 2) + 4 * kg;
        const int row = row0 + wm * 128 + mi * 32 + rr;
        base[(size_t)row * NEXP + col] = acc[mi][ni][reg];
      }
    }
}

// ---------------- Gating: one wave per token; sums S partial planes ----------------
__global__ __launch_bounds__(256) void gate_kernel(const float* __restrict__ logits,
                                                   const float* __restrict__ bias,
                                                   float* __restrict__ out_w,
                                                   float* __restrict__ out_e, int S) {
    const int wave = threadIdx.x >> 6;
    const int lane = threadIdx.x & 63;
    const int t = blockIdx.x * 4 + wave;
    if (t >= T_TOK) return;

    float l4[4] = {0.f, 0.f, 0.f, 0.f};
    for (int s = 0; s < S; ++s) {  // fixed order -> deterministic
        const float4 v = *(const float4*)(&logits[(size_t)s * PLANE + (size_t)t * NEXP + lane * 4]);
        l4[0] += v.x; l4[1] += v.y; l4[2] += v.z; l4[3] += v.w;
    }
    const float4 bv = *(const float4*)(&bias[lane * 4]);

    float s4[4], c[4];
#pragma unroll
    for (int j = 0; j < 4; ++j) s4[j] = 1.f / (1.f + expf(-l4[j] * INV_S2));
    c[0] = s4[0] + bv.x;
    c[1] = s4[1] + bv.y;
    c[2] = s4[2] + bv.z;
    c[3] = s4[3] + bv.w;

    float a = fmaxf(c[0], c[1]), b = fminf(c[0], c[1]);
    float d = fmaxf(c[2], c[3]), e = fminf(c[2], c[3]);
    float m1 = fmaxf(a, d);
    float m2 = fmaxf(fminf(a, d), fmaxf(b, e));
#pragma unroll
    for (int off = 1; off < 8; off <<= 1) {
        const float o1 = __shfl_xor(m1, off);
        const float o2 = __shfl_xor(m2, off);
        const float n1 = fmaxf(m1, o1);
        const float n2 = fmaxf(fminf(m1, o1), fmaxf(m2, o2));
        m1 = n1; m2 = n2;
    }
    const float gs = m1 + m2;
    const int   g  = lane >> 3;

    int rank = 0;
#pragma unroll
    for (int gg = 0; gg < 8; ++gg) {
        const float og = __shfl(gs, gg * 8);
        rank += (og > gs) || (og == gs && gg < g);
    }
    const bool gsel = rank < 4;

    float v[4];
#pragma unroll
    for (int j = 0; j < 4; ++j) v[j] = gsel ? c[j] : 0.0f;

    float selw = 0.f;
    int   seli = 0;
    float wsum = 0.f;

#pragma unroll
    for (int k = 0; k < 8; ++k) {
        float bvv = v[0]; int bi = lane * 4; float br = s4[0];
#pragma unroll
        for (int j = 1; j < 4; ++j) {
            if (v[j] > bvv) { bvv = v[j]; bi = lane * 4 + j; br = s4[j]; }
        }
#pragma unroll
        for (int off = 32; off > 0; off >>= 1) {
            const float ov = __shfl_xor(bvv, off);
            const int   oi = __shfl_xor(bi, off);
            const float orr = __shfl_xor(br, off);
            if (ov > bvv || (ov == bvv && oi < bi)) { bvv = ov; bi = oi; br = orr; }
        }
        if (lane == k) { selw = br; seli = bi; }
        wsum += br;
        const int rem = bi - lane * 4;
#pragma unroll
        for (int j = 0; j < 4; ++j)
            if (rem == j) v[j] = -INFINITY;
    }

    if (lane < 8) {
        const float w = selw / (wsum + 1e-20f) * 2.5f;
        out_w[(size_t)t * 8 + lane] = w;
        out_e[(size_t)t * 8 + lane] = (float)seli;
    }
}

extern "C" void kernel_launch(void* const* d_in, const int* in_sizes, int n_in,
                              void* d_out, int out_size, void* d_ws, size_t ws_size,
                              hipStream_t stream) {
    const float* X    = (const float*)d_in[0];
    const float* W    = (const float*)d_in[1];
    const float* bias = (const float*)d_in[2];
    float* out = (float*)d_out;

    _Float16* img = (_Float16*)d_ws;
    const size_t woff = (size_t)NSTEP_TOT * BIMG_STEP;   // 7,340,032 B
    float* partial = (float*)((char*)d_ws + woff);

    int S = 1;
    if (ws_size >= woff + 8 * PLANE * sizeof(float)) S = 8;       // 256 blocks = 1/CU
    else if (ws_size >= woff + 4 * PLANE * sizeof(float)) S = 4;
    else if (ws_size >= woff + 2 * PLANE * sizeof(float)) S = 2;

    wconv<<<dim3(NSTEP_TOT * 2048 / 256), 256, 0, stream>>>(W, img);
    router_gemm<<<dim3((T_TOK / BM) * S), 512, 0, stream>>>(X, img, partial, S);
    gate_kernel<<<dim3(T_TOK / 4), 256, 0, stream>>>(partial, bias, out, out + (size_t)T_TOK * 8, S);
}